// Round 3
// baseline (128.809 us; speedup 1.0000x reference)
//
#include <hip/hip_runtime.h>
#include <math.h>

#define B_SZ  1024
#define N_SZ  128
#define M_SZ  256
#define I_SZ  64
#define WAVES 8
#define CHW   (I_SZ / WAVES)   // 8 i's per wave

// One block (8 waves) per sample b. Wave w owns i in [8w, 8w+8), recomputing
// its prefix z-start via a float4 dot product (cheap, VALU pipe). Lane owns
// m = lane + {0,64,128,192}. Per-i reductions over m are intra-wave
// butterflies; per-wave psi/acc partials combine once through LDS.
// normal^2 = 4*P0^2 + 2*Pw0^2 + 2*Pw1^2; psi telescopes: cos(full_i)=cos(pre_{i+1}).
__global__ __launch_bounds__(512) void arrbm_kernel(
    const float* __restrict__ vis,     // [B,N]
    const float* __restrict__ hb,      // [M]
    const float* __restrict__ weight,  // [M,N]
    float* __restrict__ out)           // [B]
{
    const int b    = blockIdx.x;
    const int tid  = threadIdx.x;
    const int lane = tid & 63;
    const int wv   = tid >> 6;         // 0..7

    __shared__ float s_vis[N_SZ];
    __shared__ float s_red[WAVES][2];
    __shared__ float s_sz;

    if (tid < N_SZ / 4)
        ((float4*)s_vis)[tid] = ((const float4*)(vis + (size_t)b * N_SZ))[tid];
    __syncthreads();

    const int i0 = wv * CHW;

    float bias[4], z[4];
    const float2* wp[4];
    #pragma unroll
    for (int mm = 0; mm < 4; ++mm) {
        const int m = lane + mm * 64;
        bias[mm] = hb[m];
        z[mm]    = 0.0f;
        wp[mm]   = (const float2*)(weight + (size_t)m * N_SZ);
    }

    // z-start: dot over first 2*i0 elements (vectorized float4)
    {
        const int n4 = i0 >> 1;        // (2*i0)/4 float4 chunks
        for (int t = 0; t < n4; ++t) {
            const float4 sv = ((const float4*)s_vis)[t];
            #pragma unroll
            for (int mm = 0; mm < 4; ++mm) {
                const float4 w4 = ((const float4*)wp[mm])[t];
                z[mm] += sv.x * w4.x + sv.y * w4.y + sv.z * w4.z + sv.w * w4.w;
            }
        }
    }
    float zs[4];
    #pragma unroll
    for (int mm = 0; mm < 4; ++mm) zs[mm] = z[mm];

    float psi = 1.0f;   // prod of cos(pre_i) over chunk (ends corrected below)
    float acc = 1.0f;   // prod of 1/normal_i over chunk

    float r0[CHW], r1[CHW], r2[CHW];
    #pragma unroll
    for (int j = 0; j < CHW; ++j) {
        const int   i  = i0 + j;
        const float v0 = s_vis[2 * i];
        const float v1 = s_vis[2 * i + 1];
        float q0 = 1.0f, q1 = 1.0f, q2 = 1.0f;
        #pragma unroll
        for (int mm = 0; mm < 4; ++mm) {
            const float2 w   = wp[mm][i];
            const float  pre = bias[mm] + z[mm];
            const float  c0  = __cosf(pre);
            q0 *= c0;
            q1 *= __cosf(pre + w.x);
            q2 *= __cosf(pre + w.y);
            psi *= c0;
            z[mm] += v0 * w.x + v1 * w.y;
        }
        r0[j] = q0; r1[j] = q1; r2[j] = q2;
    }

    // 3*CHW independent butterfly product-reductions
    #pragma unroll
    for (int j = 0; j < CHW; ++j) {
        #pragma unroll
        for (int off = 32; off >= 1; off >>= 1) {
            r0[j] *= __shfl_xor(r0[j], off, 64);
            r1[j] *= __shfl_xor(r1[j], off, 64);
            r2[j] *= __shfl_xor(r2[j], off, 64);
        }
        acc *= rsqrtf(4.0f * r0[j] * r0[j] + 2.0f * r1[j] * r1[j] + 2.0f * r2[j] * r2[j]);
    }

    // chunk-telescope end correction: x cos(bias+z_end)/cos(bias+z_start)
    #pragma unroll
    for (int mm = 0; mm < 4; ++mm)
        psi *= __cosf(bias[mm] + z[mm]) / __cosf(bias[mm] + zs[mm]);

    // reduce psi across lanes (product)
    #pragma unroll
    for (int off = 32; off >= 1; off >>= 1)
        psi *= __shfl_xor(psi, off, 64);

    // Sz filter in wave 0
    if (wv == 0) {
        float szl = s_vis[2 * lane] - s_vis[2 * lane + 1];
        #pragma unroll
        for (int off = 32; off >= 1; off >>= 1)
            szl += __shfl_xor(szl, off, 64);
        if (lane == 0) s_sz = szl;
    }

    if (lane == 0) { s_red[wv][0] = psi; s_red[wv][1] = acc; }
    __syncthreads();

    if (tid == 0) {
        float P = 1.0f, A = 1.0f;
        #pragma unroll
        for (int w = 0; w < WAVES; ++w) { P *= s_red[w][0]; A *= s_red[w][1]; }
        out[b] = (s_sz != 0.0f) ? 0.0f : P * A;
    }
}

extern "C" void kernel_launch(void* const* d_in, const int* in_sizes, int n_in,
                              void* d_out, int out_size, void* d_ws, size_t ws_size,
                              hipStream_t stream) {
    const float* vis    = (const float*)d_in[0];  // [B,N]
    const float* hb     = (const float*)d_in[1];  // [M]
    const float* weight = (const float*)d_in[2];  // [M,N]
    float* out = (float*)d_out;                   // [B]

    arrbm_kernel<<<B_SZ, 64 * WAVES, 0, stream>>>(vis, hb, weight, out);
}